// Round 1
// baseline (767.634 us; speedup 1.0000x reference)
//
#include <hip/hip_runtime.h>

#define N_TOK 16384
#define D 64
#define NC 512
#define KSEL 16

// ---------------- kernel A: center squared norms ----------------
__global__ void c2_kernel(const float* __restrict__ ctrs, float* __restrict__ c2) {
    int c = blockIdx.x * blockDim.x + threadIdx.x;
    if (c < NC) {
        const float4* row = (const float4*)(ctrs + c * D);
        float s = 0.f;
        #pragma unroll
        for (int i = 0; i < D / 4; ++i) {
            float4 v = row[i];
            s += v.x * v.x + v.y * v.y + v.z * v.z + v.w * v.w;
        }
        c2[c] = s;
    }
}

// ---------------- kernel B: fused dist GEMM + top-16 + softmax ----------------
// 64 tokens per block, 256 threads. s[n,c] = 2*x.c - ||c||^2 (x^2 shift cancels
// in both top-k ordering and softmax).
__global__ __launch_bounds__(256) void topk_kernel(
    const float* __restrict__ x, const float* __restrict__ ctrs,
    const float* __restrict__ c2, float* __restrict__ scores,
    int* __restrict__ sidx) {
    __shared__ float xsT[D * 65];   // xsT[g*65 + token]
    __shared__ float cs[D * 130];   // csT[g*130 + c]; aliased as Stile[token*130 + c]

    const int t = threadIdx.x;
    const int tt = t & 15;   // token group: tokens tt*4 .. tt*4+3
    const int cc = t >> 4;   // center group: centers cc*8 .. cc*8+7 (within chunk)
    const int tokbase = blockIdx.x * 64;

    // stage x tile, transposed
    {
        const float4* x4 = (const float4*)(x + tokbase * D);
        #pragma unroll
        for (int i = 0; i < 4; ++i) {
            int e = t + 256 * i;            // 0..1023
            int r = e >> 4, j = e & 15;     // token r, float4 j
            float4 v = x4[e];
            xsT[(4 * j + 0) * 65 + r] = v.x;
            xsT[(4 * j + 1) * 65 + r] = v.y;
            xsT[(4 * j + 2) * 65 + r] = v.z;
            xsT[(4 * j + 3) * 65 + r] = v.w;
        }
    }

    float tv[KSEL];
    int   ti[KSEL];
    #pragma unroll
    for (int i = 0; i < KSEL; ++i) { tv[i] = -1e30f; ti[i] = 0; }

    for (int chunk = 0; chunk < 4; ++chunk) {
        const int cbase = chunk * 128;
        __syncthreads();  // prior Stile reads done (and xsT ready on first iter)

        // stage 128-center chunk, transposed
        const float4* c4 = (const float4*)(ctrs + cbase * D);
        #pragma unroll
        for (int i = 0; i < 8; ++i) {
            int e = t + 256 * i;            // 0..2047
            int r = e >> 4, j = e & 15;     // center r (0..127), float4 j
            float4 v = c4[e];
            cs[(4 * j + 0) * 130 + r] = v.x;
            cs[(4 * j + 1) * 130 + r] = v.y;
            cs[(4 * j + 2) * 130 + r] = v.z;
            cs[(4 * j + 3) * 130 + r] = v.w;
        }
        __syncthreads();

        float acc[4][8];
        #pragma unroll
        for (int i = 0; i < 4; ++i)
            #pragma unroll
            for (int j = 0; j < 8; ++j) acc[i][j] = 0.f;

        for (int g = 0; g < D; ++g) {
            float xa[4];
            #pragma unroll
            for (int i = 0; i < 4; ++i) xa[i] = xsT[g * 65 + tt * 4 + i];
            float cb[8];
            #pragma unroll
            for (int j = 0; j < 8; ++j) cb[j] = cs[g * 130 + cc * 8 + j];
            #pragma unroll
            for (int i = 0; i < 4; ++i)
                #pragma unroll
                for (int j = 0; j < 8; ++j) acc[i][j] += xa[i] * cb[j];
        }
        __syncthreads();  // everyone done reading cs -> reuse as S-tile

        #pragma unroll
        for (int i = 0; i < 4; ++i)
            #pragma unroll
            for (int j = 0; j < 8; ++j) {
                int tok = tt * 4 + i, c = cc * 8 + j;
                cs[tok * 130 + c] = 2.f * acc[i][j] - c2[cbase + c];
            }
        __syncthreads();

        if (t < 64) {  // one thread per token merges 128 candidates
            for (int c = 0; c < 128; ++c) {
                float v = cs[t * 130 + c];
                if (v > tv[KSEL - 1]) {
                    float cv = v; int ci = cbase + c;
                    #pragma unroll
                    for (int i = 0; i < KSEL; ++i) {
                        if (cv > tv[i]) {
                            float a = tv[i]; int b = ti[i];
                            tv[i] = cv; ti[i] = ci;
                            cv = a; ci = b;
                        }
                    }
                }
            }
        }
    }

    if (t < 64) {
        // softmax over the 16 selected (sorted desc -> tv[0] is max)
        float m = tv[0];
        float e[KSEL];
        float sum = 0.f;
        #pragma unroll
        for (int i = 0; i < KSEL; ++i) { e[i] = __expf(tv[i] - m); sum += e[i]; }
        float inv = 1.f / sum;
        int n = tokbase + t;
        #pragma unroll
        for (int i = 0; i < KSEL; ++i) {
            scores[n * KSEL + i] = e[i] * inv;
            sidx[n * KSEL + i] = ti[i];
        }
    }
}

// ---------------- kernel C: per-token affine mixing ----------------
// One wave per token; lane p computes out[n][p].
__global__ __launch_bounds__(256) void mix_kernel(
    const float* __restrict__ x, const float* __restrict__ Wv,
    const float* __restrict__ Ov, const float* __restrict__ scores,
    const int* __restrict__ sidx, float* __restrict__ out) {
    const int lane = threadIdx.x & 63;
    const int wave = threadIdx.x >> 6;
    const int n = blockIdx.x * 4 + wave;

    const float xr = x[n * D + lane];
    float acc = 0.f;

    #pragma unroll 1
    for (int j = 0; j < KSEL; ++j) {
        const int c = sidx[n * KSEL + j];
        const float s = scores[n * KSEL + j];
        const float* W = Wv + c * (D * D) + lane;
        float tmp = 0.f;
        #pragma unroll
        for (int g = 0; g < D; ++g) {
            tmp += __shfl(xr, g, 64) * W[g * 64];
        }
        acc += s * (tmp + Ov[c * D + lane]);
    }
    out[n * D + lane] = acc;
}

extern "C" void kernel_launch(void* const* d_in, const int* in_sizes, int n_in,
                              void* d_out, int out_size, void* d_ws, size_t ws_size,
                              hipStream_t stream) {
    const float* x    = (const float*)d_in[0];
    const float* ctrs = (const float*)d_in[1];
    const float* Wv   = (const float*)d_in[2];
    const float* Ov   = (const float*)d_in[3];
    float* out = (float*)d_out;

    float* c2     = (float*)d_ws;
    float* scores = c2 + NC;
    int*   sidx   = (int*)(scores + N_TOK * KSEL);

    hipLaunchKernelGGL(c2_kernel, dim3(2), dim3(256), 0, stream, ctrs, c2);
    hipLaunchKernelGGL(topk_kernel, dim3(N_TOK / 64), dim3(256), 0, stream,
                       x, ctrs, c2, scores, sidx);
    hipLaunchKernelGGL(mix_kernel, dim3(N_TOK / 4), dim3(256), 0, stream,
                       x, Wv, Ov, scores, sidx, out);
}